// Round 4
// baseline (177.791 us; speedup 1.0000x reference)
//
#include <hip/hip_runtime.h>

__device__ __forceinline__ void row_math(
    float p04, float p13, float p14, float p22, float p23, float p24,
    float p31, float p32, float p33, float p34,
    float p40, float p41, float p42, float p43, float p44,
    float m31, float m22, float m13, float m04,
    float* r1, float* r2) {
  // p1: mask multiplies only the LAST product term (Python precedence)
  r1[0] = 0.f;
  r1[1] = p40 * p41 * m31;
  r1[2] = p40 * p42 + p31 * p32 * m22;
  r1[3] = p40 * p43 + p31 * p33 + p22 * p23 * m13;
  r1[4] = p40 * p44 + p31 * p34 + p22 * p24 + p13 * p14 * m04;
  float q40 = 1.f - p40, q31 = 1.f - p31, q22 = 1.f - p22, q13 = 1.f - p13;
  r2[0] = 0.f;
  r2[1] = q31 * (1.f - q40) * m31;
  r2[2] = q22 * (1.f - q40 * q31) * m22;
  r2[3] = q13 * (1.f - q40 * q31 * q22) * m13;
  r2[4] = (1.f - p04) * (1.f - q40 * q31 * q22 * q13) * m04;
}

__global__ __launch_bounds__(256) void returning_rate_kernel(
    const float* __restrict__ pred, const float* __restrict__ mask,
    float* __restrict__ out, int B) {
  long long u = (long long)blockIdx.x * blockDim.x + threadIdx.x;
  long long row0 = u * 4;
  if (row0 >= B) return;

  if (row0 + 4 <= B) {
    // ---- fast path: 4 rows, per-thread-contiguous vector loads ----
    const float* prBase = pred + row0 * 25;   // 400B per thread, 16B aligned
    const float* mkBase = mask + row0 * 25;
    float o1v[20], o2v[20];

    #pragma unroll
    for (int r = 0; r < 4; ++r) {
      // row floats 25r+4 .. 25r+24 live in float4 chunks 6r+1 .. 6r+6
      // a[] holds floats 24r+4 .. 24r+27; row float j -> a[r + j - 4]
      float a[24];
      #pragma unroll
      for (int c = 0; c < 6; ++c) {
        float4 v;
        __builtin_memcpy(&v, prBase + (6 * r + 1 + c) * 4, 16);
        a[c * 4 + 0] = v.x; a[c * 4 + 1] = v.y;
        a[c * 4 + 2] = v.z; a[c * 4 + 3] = v.w;
      }
      float m04 = mkBase[25 * r + 4];
      float m13 = mkBase[25 * r + 8];
      float m22 = mkBase[25 * r + 12];
      float m31 = mkBase[25 * r + 16];

      row_math(a[r + 0],
               a[r + 4],  a[r + 5],
               a[r + 8],  a[r + 9],  a[r + 10],
               a[r + 12], a[r + 13], a[r + 14], a[r + 15],
               a[r + 16], a[r + 17], a[r + 18], a[r + 19], a[r + 20],
               m31, m22, m13, m04,
               &o1v[5 * r], &o2v[5 * r]);
    }

    // ---- packed stores: 20 floats each region = 5 float4, thread-contiguous ----
    float* o1 = out + row0 * 5;
    float* o2 = out + (size_t)B * 5 + row0 * 5;
    #pragma unroll
    for (int k = 0; k < 5; ++k) {
      __builtin_memcpy(o1 + 4 * k, &o1v[4 * k], 16);
      __builtin_memcpy(o2 + 4 * k, &o2v[4 * k], 16);
    }
  } else {
    // ---- tail: scalar per-row ----
    for (long long s = row0; s < B; ++s) {
      const float* pr = pred + s * 25;
      const float* mk = mask + s * 25;
      float r1[5], r2[5];
      row_math(pr[4], pr[8], pr[9], pr[12], pr[13], pr[14],
               pr[16], pr[17], pr[18], pr[19],
               pr[20], pr[21], pr[22], pr[23], pr[24],
               mk[16], mk[12], mk[8], mk[4], r1, r2);
      float* o1 = out + s * 5;
      float* o2 = out + (size_t)B * 5 + s * 5;
      for (int k = 0; k < 5; ++k) { o1[k] = r1[k]; o2[k] = r2[k]; }
    }
  }
}

extern "C" void kernel_launch(void* const* d_in, const int* in_sizes, int n_in,
                              void* d_out, int out_size, void* d_ws, size_t ws_size,
                              hipStream_t stream) {
  const float* pred = (const float*)d_in[0];
  const float* mask = (const float*)d_in[1];
  float* out = (float*)d_out;
  int B = in_sizes[0] / 25;

  long long threads = ((long long)B + 3) / 4;
  int blocks = (int)((threads + 255) / 256);
  returning_rate_kernel<<<blocks, 256, 0, stream>>>(pred, mask, out, B);
}

// Round 6
// 88.504 us; speedup vs baseline: 2.0088x; 2.0088x over previous
//
#include <hip/hip_runtime.h>

#define TILE 256

typedef float f32x4 __attribute__((ext_vector_type(4)));

__global__ __launch_bounds__(256) void returning_rate_kernel(
    const float* __restrict__ pred, const float* __restrict__ mask,
    float* __restrict__ out, int B) {
  __shared__ float o1s[TILE * 5];
  __shared__ float o2s[TILE * 5];

  const int t = threadIdx.x;
  const long long blockRow = (long long)blockIdx.x * TILE;
  const long long s = blockRow + t;
  const int nrows = (int)((blockRow + TILE <= (long long)B) ? TILE : ((long long)B - blockRow));

  if (t < nrows) {
    const float* pr = pred + s * 25;
    const float* mk = mask + s * 25;

    // pred[i][j] -> flat i*5+j  (proven-fastest scalar load path from R1)
    float p40 = pr[20], p41 = pr[21], p42 = pr[22], p43 = pr[23], p44 = pr[24];
    float p31 = pr[16], p32 = pr[17], p33 = pr[18], p34 = pr[19];
    float p22 = pr[12], p23 = pr[13], p24 = pr[14];
    float p13 = pr[8],  p14 = pr[9];
    float p04 = pr[4];
    float m31 = mk[16], m22 = mk[12], m13 = mk[8], m04 = mk[4];

    // p1: mask multiplies only the LAST product term (Python precedence)
    float p1_1 = p40 * p41 * m31;
    float p1_2 = p40 * p42 + p31 * p32 * m22;
    float p1_3 = p40 * p43 + p31 * p33 + p22 * p23 * m13;
    float p1_4 = p40 * p44 + p31 * p34 + p22 * p24 + p13 * p14 * m04;

    float q40 = 1.f - p40, q31 = 1.f - p31, q22 = 1.f - p22, q13 = 1.f - p13;
    float p2_1 = q31 * (1.f - q40) * m31;
    float p2_2 = q22 * (1.f - q40 * q31) * m22;
    float p2_3 = q13 * (1.f - q40 * q31 * q22) * m13;
    float p2_4 = (1.f - p04) * (1.f - q40 * q31 * q22 * q13) * m04;

    // pack to LDS (stride 5 -> gcd(5,32)=1 -> 2 lanes/bank, free)
    float* a = o1s + t * 5;
    a[0] = 0.f; a[1] = p1_1; a[2] = p1_2; a[3] = p1_3; a[4] = p1_4;
    float* b = o2s + t * 5;
    b[0] = 0.f; b[1] = p2_1; b[2] = p2_2; b[3] = p2_3; b[4] = p2_4;
  }
  __syncthreads();

  // Full-line non-temporal float4 stores: keep 80MB of dead output writes out
  // of L3 so it can hold more of the 400MB input read-set across replays.
  const int nfloats = nrows * 5;          // 1280 (full) or tail
  const int nv4 = nfloats / 4;
  float* g1 = out + blockRow * 5;         // blockRow*5*4 = 5120*bid bytes -> 16B aligned
  float* g2 = out + (long long)B * 5 + blockRow * 5;  // B*20 bytes divisible by 16

  for (int i = t; i < nv4; i += 256) {
    f32x4 v1, v2;
    __builtin_memcpy(&v1, &o1s[i * 4], 16);
    __builtin_memcpy(&v2, &o2s[i * 4], 16);
    __builtin_nontemporal_store(v1, (f32x4*)g1 + i);
    __builtin_nontemporal_store(v2, (f32x4*)g2 + i);
  }
  for (int i = nv4 * 4 + t; i < nfloats; i += 256) {  // remainder (none for B=2M)
    g1[i] = o1s[i];
    g2[i] = o2s[i];
  }
}

extern "C" void kernel_launch(void* const* d_in, const int* in_sizes, int n_in,
                              void* d_out, int out_size, void* d_ws, size_t ws_size,
                              hipStream_t stream) {
  const float* pred = (const float*)d_in[0];
  const float* mask = (const float*)d_in[1];
  float* out = (float*)d_out;
  int B = in_sizes[0] / 25;

  int blocks = (int)(((long long)B + TILE - 1) / TILE);
  returning_rate_kernel<<<blocks, 256, 0, stream>>>(pred, mask, out, B);
}

// Round 7
// 88.034 us; speedup vs baseline: 2.0196x; 1.0053x over previous
//
#include <hip/hip_runtime.h>

#define TILE 256

typedef float f32x4 __attribute__((ext_vector_type(4)));

__device__ __forceinline__ void stage16(const float* g, float* l) {
  __builtin_amdgcn_global_load_lds(
      (const __attribute__((address_space(1))) void*)g,
      (__attribute__((address_space(3))) void*)l, 16, 0, 0);
}

__global__ __launch_bounds__(256) void returning_rate_kernel(
    const float* __restrict__ pred, const float* __restrict__ mask,
    float* __restrict__ out, int B) {
  __shared__ float tileP[TILE * 25];   // 25.6 KB pred stage
  __shared__ float o1s[TILE * 5];      // 5.12 KB
  __shared__ float o2s[TILE * 5];      // 5.12 KB

  const int t = threadIdx.x;
  const long long blockRow = (long long)blockIdx.x * TILE;
  const bool full = (blockRow + TILE <= (long long)B);

  float p40, p41, p42, p43, p44, p31, p32, p33, p34;
  float p22, p23, p24, p13, p14, p04, m31, m22, m13, m04;

  if (full) {
    // ---- async stage pred tile: 1600 lane-chunks of 16B, contiguous per wave ----
    const float* src = pred + blockRow * 25;
    #pragma unroll
    for (int k = 0; k < 7; ++k) {
      int i = k * 256 + t;                 // f32x4 chunk index
      if (i < TILE * 25 / 4) stage16(src + i * 4, tileP + i * 4);
    }
    // ---- mask: only 4 elements/row needed; scalar loads overlap the staging ----
    const float* mk = mask + (blockRow + t) * 25;
    m04 = mk[4]; m13 = mk[8]; m22 = mk[12]; m31 = mk[16];

    __syncthreads();   // drains vmcnt(0): staging + mask loads complete

    const float* r = tileP + t * 25;     // stride-25 -> 2 lanes/bank, free
    p40 = r[20]; p41 = r[21]; p42 = r[22]; p43 = r[23]; p44 = r[24];
    p31 = r[16]; p32 = r[17]; p33 = r[18]; p34 = r[19];
    p22 = r[12]; p23 = r[13]; p24 = r[14];
    p13 = r[8];  p14 = r[9];
    p04 = r[4];
  } else {
    // ---- tail block (<=1 block): scalar path, no staging ----
    const long long s = blockRow + t;
    const float* pr = pred + s * 25;
    const float* mk = mask + s * 25;
    bool act = s < (long long)B;
    const float* prs = act ? pr : pred;   // safe dummy
    const float* mks = act ? mk : mask;
    p40 = prs[20]; p41 = prs[21]; p42 = prs[22]; p43 = prs[23]; p44 = prs[24];
    p31 = prs[16]; p32 = prs[17]; p33 = prs[18]; p34 = prs[19];
    p22 = prs[12]; p23 = prs[13]; p24 = prs[14];
    p13 = prs[8];  p14 = prs[9];
    p04 = prs[4];
    m31 = mks[16]; m22 = mks[12]; m13 = mks[8]; m04 = mks[4];
    __syncthreads();
  }

  // ---- compute ----
  // p1: mask multiplies only the LAST product term (Python precedence)
  float p1_1 = p40 * p41 * m31;
  float p1_2 = p40 * p42 + p31 * p32 * m22;
  float p1_3 = p40 * p43 + p31 * p33 + p22 * p23 * m13;
  float p1_4 = p40 * p44 + p31 * p34 + p22 * p24 + p13 * p14 * m04;

  float q40 = 1.f - p40, q31 = 1.f - p31, q22 = 1.f - p22, q13 = 1.f - p13;
  float p2_1 = q31 * (1.f - q40) * m31;
  float p2_2 = q22 * (1.f - q40 * q31) * m22;
  float p2_3 = q13 * (1.f - q40 * q31 * q22) * m13;
  float p2_4 = (1.f - p04) * (1.f - q40 * q31 * q22 * q13) * m04;

  const long long s = blockRow + t;
  const int nrows = (int)(full ? TILE : ((long long)B > blockRow ? (long long)B - blockRow : 0));

  if (t < nrows) {
    float* a = o1s + t * 5;   // stride 5 -> 2 lanes/bank, free
    a[0] = 0.f; a[1] = p1_1; a[2] = p1_2; a[3] = p1_3; a[4] = p1_4;
    float* b = o2s + t * 5;
    b[0] = 0.f; b[1] = p2_1; b[2] = p2_2; b[3] = p2_3; b[4] = p2_4;
  }
  __syncthreads();

  // ---- full-line non-temporal float4 stores (R6's proven path) ----
  const int nfloats = nrows * 5;
  const int nv4 = nfloats / 4;
  float* g1 = out + blockRow * 5;                      // 5120*bid B -> 16B aligned
  float* g2 = out + (long long)B * 5 + blockRow * 5;   // B*20 B divisible by 16

  for (int i = t; i < nv4; i += 256) {
    f32x4 v1, v2;
    __builtin_memcpy(&v1, &o1s[i * 4], 16);
    __builtin_memcpy(&v2, &o2s[i * 4], 16);
    __builtin_nontemporal_store(v1, (f32x4*)g1 + i);
    __builtin_nontemporal_store(v2, (f32x4*)g2 + i);
  }
  for (int i = nv4 * 4 + t; i < nfloats; i += 256) {
    g1[i] = o1s[i];
    g2[i] = o2s[i];
  }
}

extern "C" void kernel_launch(void* const* d_in, const int* in_sizes, int n_in,
                              void* d_out, int out_size, void* d_ws, size_t ws_size,
                              hipStream_t stream) {
  const float* pred = (const float*)d_in[0];
  const float* mask = (const float*)d_in[1];
  float* out = (float*)d_out;
  int B = in_sizes[0] / 25;

  int blocks = (int)(((long long)B + TILE - 1) / TILE);
  returning_rate_kernel<<<blocks, 256, 0, stream>>>(pred, mask, out, B);
}